// Round 19
// baseline (950.134 us; speedup 1.0000x reference)
//
#include <hip/hip_runtime.h>
#include <hip/hip_bf16.h>
#include <cstddef>

#define HD 512

typedef short s8v __attribute__((ext_vector_type(8)));
typedef short s4v __attribute__((ext_vector_type(4)));
typedef float fx4 __attribute__((ext_vector_type(4)));

#define MFMA(a, b, c) __builtin_amdgcn_mfma_f32_16x16x32_bf16((a), (b), (c), 0, 0, 0)

__device__ __forceinline__ unsigned short f2bf(float f) {
  unsigned int u = __float_as_uint(f);
  unsigned int r = (u + 0x7fffu + ((u >> 16) & 1u)) >> 16;
  return (unsigned short)r;
}
__device__ __forceinline__ float bf2f(unsigned short u) {
  return __uint_as_float(((unsigned int)u) << 16);
}

// Swizzled B-operand layout for 16x16x32 MFMA (R1/R3-proven):
// element (k,n) -> chunk (ntile*KT + kt); lane = ((k&31)>>3)<<4 | (n&15); i = k&7
__device__ __forceinline__ size_t swz_off(int k, int n, int KT) {
  int kt = k >> 5, kr = k & 31;
  int nt = n >> 4, nr = n & 15;
  int lane = ((kr >> 3) << 4) | nr;
  int i = kr & 7;
  return ((((size_t)nt * KT + kt) * 64 + lane) << 3) + i;
}

// ---------------- pack weights (R4-proven layouts) ----------------
__global__ void pack_kernel(const float* w_r, const float* ur, const float* wz, const float* wh,
                            const float* wo,
                            unsigned short* W1, unsigned short* WZB, unsigned short* WHB,
                            unsigned short* WUR, unsigned short* WO) {
  int idx = blockIdx.x * blockDim.x + threadIdx.x;
  int stride = gridDim.x * blockDim.x;
  for (int t = idx; t < 512 * 1536; t += stride) {
    int k = t / 1536, n = t - k * 1536;
    float v;
    if (n < 512) v = w_r[k * 512 + n];
    else if (n < 1024) v = wz[k * 512 + (n - 512)];
    else v = wh[k * 512 + (n - 1024)];
    W1[swz_off(k, n, 16)] = f2bf(v);
  }
  for (int t = idx; t < 512 * 512; t += stride) {
    int k = t >> 9, n = t & 511;
    size_t o = swz_off(k, n, 16);
    WZB[o] = f2bf(wz[(512 + k) * 512 + n]);
    WHB[o] = f2bf(wh[(512 + k) * 512 + n]);
    WUR[o] = f2bf(ur[k * 512 + n]);
  }
  for (int t = idx; t < 1024 * 512; t += stride) {
    int k = t >> 9, n = t & 511;
    WO[swz_off(k, n, 32)] = f2bf(wo[k * 512 + n]);
  }
}

// ---------------- embedding gather ----------------
__global__ void embed_kernel(const int* wid, const float* emb, unsigned short* x_bf, int BN) {
  int idx = blockIdx.x * blockDim.x + threadIdx.x;
  int stride = gridDim.x * blockDim.x;
  int total = BN * (HD / 8);
  for (int t = idx; t < total; t += stride) {
    int nrow = t >> 6;
    int c8 = (t & 63) << 3;
    int w = wid[nrow];
    const float4* s = (const float4*)(emb + (size_t)w * HD + c8);
    float4 v0 = s[0], v1 = s[1];
    s8v o;
    o[0] = (short)f2bf(v0.x); o[1] = (short)f2bf(v0.y);
    o[2] = (short)f2bf(v0.z); o[3] = (short)f2bf(v0.w);
    o[4] = (short)f2bf(v1.x); o[5] = (short)f2bf(v1.y);
    o[6] = (short)f2bf(v1.z); o[7] = (short)f2bf(v1.w);
    *(s8v*)&x_bf[(size_t)nrow * HD + c8] = o;
  }
}

// ---------------- schedule ----------------
__global__ void schedule_kernel(const int* preds, int E, int Epc, int P, int* sched) {
  __shared__ int rnd[64];
  int t = threadIdx.x;
  rnd[t] = -1;
  __syncthreads();
  for (int it = 0; it <= Epc; ++it) {
    int newv = -1;
    if (t < Epc && rnd[t] < 0) {
      int mx = 0;
      bool ready = true;
      for (int q = 0; q < P; ++q) {
        int pe = preds[t * P + q];
        if (pe < E) {
          int rp = rnd[pe];
          if (rp < 0) ready = false;
          else if (rp + 1 > mx) mx = rp + 1;
        }
      }
      if (ready) newv = mx;
    }
    __syncthreads();
    if (newv >= 0) rnd[t] = newv;
    __syncthreads();
  }
  if (t == 0) {
    int R = 0;
    for (int e = 0; e < Epc; ++e) if (rnd[e] + 1 > R) R = rnd[e] + 1;
    if (R > 31) R = 31;
    sched[0] = R;
    for (int r = 0; r < 31; ++r) {
      int c = 0;
      if (r < R) {
        for (int e = 0; e < Epc; ++e) if (rnd[e] == r) { sched[33 + r * 32 + c] = e; ++c; }
      }
      sched[1 + r] = c;
    }
  }
}

// ---------------- XP = x_bf @ W1: 8-wave, 128r x 256c per block, 6 col-slabs (R8) ----------------
__global__ __launch_bounds__(512, 4) void gemm_pre_kernel(const unsigned short* x_bf,
                                                          const unsigned short* W1,
                                                          unsigned short* XP, int BN) {
  __shared__ unsigned short lA[2][128 * 72];
  const int nM = BN >> 7;
  const int slab = blockIdx.x / nM;
  const int mt = blockIdx.x - slab * nM;
  const int tid = threadIdx.x, lane = tid & 63, w = tid >> 6;
  const int wm = w & 1, wn = w >> 1;
  const int m0 = mt << 7;
  const int srow = tid >> 2, sc0 = (tid & 3) << 4;
  const int k8 = (lane >> 4) << 3;
  fx4 ac[16];
#pragma unroll
  for (int i = 0; i < 16; i++) { ac[i][0]=0.f; ac[i][1]=0.f; ac[i][2]=0.f; ac[i][3]=0.f; }
  const unsigned short* aptr = x_bf + (size_t)(m0 + srow) * 512 + sc0;
  s8v r0, r1;
  {
    r0 = *(const s8v*)aptr;
    r1 = *(const s8v*)(aptr + 8);
    *(s8v*)&lA[0][srow * 72 + sc0]     = r0;
    *(s8v*)&lA[0][srow * 72 + sc0 + 8] = r1;
    r0 = *(const s8v*)(aptr + 64);
    r1 = *(const s8v*)(aptr + 72);
  }
  for (int ks = 0; ks < 8; ++ks) {
    const int cur = ks & 1;
    __syncthreads();
    if (ks < 7) {
      *(s8v*)&lA[cur ^ 1][srow * 72 + sc0]     = r0;
      *(s8v*)&lA[cur ^ 1][srow * 72 + sc0 + 8] = r1;
    }
    if (ks < 6) {
      const unsigned short* g = aptr + ((ks + 2) << 6);
      r0 = *(const s8v*)g;
      r1 = *(const s8v*)(g + 8);
    }
#pragma unroll
    for (int sub = 0; sub < 2; ++sub) {
      const int kt = (ks << 1) + sub;
      s8v a[4];
#pragma unroll
      for (int mi = 0; mi < 4; ++mi)
        a[mi] = *(const s8v*)&lA[cur][((wm << 6) + (mi << 4) + (lane & 15)) * 72 + (sub << 5) + k8];
#pragma unroll
      for (int ni = 0; ni < 4; ++ni) {
        const int ntile = (slab << 4) + (wn << 2) + ni;
        const s8v b = *(const s8v*)(W1 + ((((size_t)ntile << 4) + kt) * 64 + lane) * 8);
#pragma unroll
        for (int mi = 0; mi < 4; ++mi) ac[mi * 4 + ni] = MFMA(a[mi], b, ac[mi * 4 + ni]);
      }
    }
  }
#pragma unroll
  for (int mi = 0; mi < 4; ++mi) {
#pragma unroll
    for (int q = 0; q < 4; ++q) {
      const int row = (wm << 6) + (mi << 4) + ((lane >> 4) << 2) + q;
#pragma unroll
      for (int ni = 0; ni < 4; ++ni) {
        const int col = (slab << 8) + (wn << 6) + (ni << 4) + (lane & 15);
        XP[(size_t)(m0 + row) * 1536 + col] = f2bf(ac[mi * 4 + ni][q]);
      }
    }
  }
}

// ---------------- phase A: gather; hu interleaved reads; contiguous per-wave chunks ----------------
struct AP {
  const int* sched;
  const int* preds;
  const int* edge_src;
  const float* ur_b;
  const unsigned short* XP;
  const unsigned short* hu_c;   // [E][1024]: h(0..511) | u(512..1023)
  unsigned short* A2h;
  unsigned short* A2g;
  int* eIdx;
  int* srcIdx;
  int B, Epc, P, E;
};

__global__ __launch_bounds__(256) void gatherA_kernel(AP p, int r) {
  const int cnt = p.sched[1 + r];
  if (cnt == 0) return;
  const int M = cnt * p.B;
  const int* lst = p.sched + 33 + r * 32;
  const int lane = threadIdx.x & 63;
  const int waveId = blockIdx.x * 4 + (threadIdx.x >> 6);
  const int totalWaves = gridDim.x * 4;
  const int chunk = (M + totalWaves - 1) / totalWaves;
  const int mBeg = waveId * chunk;
  const int mEnd = (mBeg + chunk < M) ? (mBeg + chunk) : M;
  for (int m = mBeg; m < mEnd; ++m) {
    const int b = m / cnt;
    const int j = m - b * cnt;
    const int e = b * p.Epc + lst[j];
    const int src = p.edge_src[e];
    if (lane == 0) { p.eIdx[m] = e; p.srcIdx[m] = src; }
    const int c0 = lane << 3;
    const s8v xr8 = *(const s8v*)&p.XP[(size_t)src * 1536 + c0];
    float xb[8], ub[8], sh[8], sg[8];
#pragma unroll
    for (int i = 0; i < 8; i++) {
      xb[i] = bf2f((unsigned short)xr8[i]);
      ub[i] = p.ur_b[c0 + i];
      sh[i] = 0.f; sg[i] = 0.f;
    }
    for (int t = 0; t < p.P; ++t) {
      const int pe = p.preds[(size_t)e * p.P + t];
      if (pe >= p.E) continue;
      const unsigned short* hurow = p.hu_c + (size_t)pe * 1024;
      const s8v h8 = *(const s8v*)&hurow[c0];
      const s8v u8 = *(const s8v*)&hurow[512 + c0];
#pragma unroll
      for (int i = 0; i < 8; i++) {
        const float hv = bf2f((unsigned short)h8[i]);
        const float rr = 1.f / (1.f + __expf(-(xb[i] + bf2f((unsigned short)u8[i]) + ub[i])));
        sh[i] += hv;
        sg[i] += rr * hv;
      }
    }
    s8v shb, sgb;
#pragma unroll
    for (int i = 0; i < 8; i++) { shb[i] = (short)f2bf(sh[i]); sgb[i] = (short)f2bf(sg[i]); }
    *(s8v*)&p.A2h[(size_t)m * 512 + c0] = shb;
    *(s8v*)&p.A2g[(size_t)m * 512 + c0] = sgb;
  }
}

// ---------------- phase B: 4-wave dual GEMM 32r x 256c (K=512) -> hu h-half ----------------
struct BP {
  const int* sched;
  const float* wz_b;
  const float* wh_b;
  const unsigned short* XP;
  const unsigned short* A2h;
  const unsigned short* A2g;
  const unsigned short* WZB;
  const unsigned short* WHB;
  const int* eIdx;
  const int* srcIdx;
  unsigned short* hu;
  int B;
};

__global__ __launch_bounds__(256, 4) void gemmB_kernel(BP p, int r) {
  const int cnt = p.sched[1 + r];
  if (cnt == 0) return;
  const int M = cnt * p.B;
  const int nT = (M >> 5) << 1;
  const int qq = nT >> 3;
  __shared__ unsigned short lZ[2][32 * 72];
  __shared__ unsigned short lH[2][32 * 72];
  __shared__ int eL[32];
  __shared__ int sL[32];
  const int tid = threadIdx.x, lane = tid & 63, w = tid >> 6;
  const int srow = tid >> 3, sc = (tid & 7) << 3;
  const int k8 = (lane >> 4) << 3;

  for (int t0 = blockIdx.x; t0 < nT; t0 += gridDim.x) {
    const int t = (t0 & 7) * qq + (t0 >> 3);
    const int mt = t >> 1, nb = t & 1;
    const int m0 = mt << 5, n0 = nb << 8;
    if (tid < 32) { eL[tid] = p.eIdx[m0 + tid]; sL[tid] = p.srcIdx[m0 + tid]; }
    fx4 aZ[8], aH[8];
#pragma unroll
    for (int i = 0; i < 8; i++) {
      aZ[i][0]=0.f; aZ[i][1]=0.f; aZ[i][2]=0.f; aZ[i][3]=0.f;
      aH[i][0]=0.f; aH[i][1]=0.f; aH[i][2]=0.f; aH[i][3]=0.f;
    }
    const size_t rbase = (size_t)(m0 + srow) * 512 + sc;
    s8v nh, ng;
    {
      *(s8v*)&lZ[0][srow * 72 + sc] = *(const s8v*)&p.A2h[rbase];
      *(s8v*)&lH[0][srow * 72 + sc] = *(const s8v*)&p.A2g[rbase];
      nh = *(const s8v*)&p.A2h[rbase + 64];
      ng = *(const s8v*)&p.A2g[rbase + 64];
    }
    for (int ks = 0; ks < 8; ++ks) {
      const int cur = ks & 1;
      __syncthreads();
      if (ks < 7) {
        *(s8v*)&lZ[cur ^ 1][srow * 72 + sc] = nh;
        *(s8v*)&lH[cur ^ 1][srow * 72 + sc] = ng;
      }
      if (ks < 6) {
        nh = *(const s8v*)&p.A2h[rbase + ((ks + 2) << 6)];
        ng = *(const s8v*)&p.A2g[rbase + ((ks + 2) << 6)];
      }
#pragma unroll
      for (int sub = 0; sub < 2; ++sub) {
        const int kt = (ks << 1) + sub;
        s8v az[2], ah[2];
#pragma unroll
        for (int mi = 0; mi < 2; ++mi) {
          const int ao = ((mi << 4) + (lane & 15)) * 72 + (sub << 5) + k8;
          az[mi] = *(const s8v*)&lZ[cur][ao];
          ah[mi] = *(const s8v*)&lH[cur][ao];
        }
#pragma unroll
        for (int ni = 0; ni < 4; ++ni) {
          const int ntile = (n0 >> 4) + (w << 2) + ni;
          const size_t boff = ((((size_t)ntile << 4) + kt) * 64 + lane) << 3;
          const s8v bz = *(const s8v*)(p.WZB + boff);
          const s8v bh = *(const s8v*)(p.WHB + boff);
#pragma unroll
          for (int mi = 0; mi < 2; ++mi) {
            aZ[mi * 4 + ni] = MFMA(az[mi], bz, aZ[mi * 4 + ni]);
            aH[mi * 4 + ni] = MFMA(ah[mi], bh, aH[mi * 4 + ni]);
          }
        }
      }
    }
#pragma unroll
    for (int mi = 0; mi < 2; ++mi) {
#pragma unroll
      for (int q4 = 0; q4 < 4; ++q4) {
        const int row = (mi << 4) + ((lane >> 4) << 2) + q4;
        const int e = eL[row];
        const int src = sL[row];
#pragma unroll
        for (int ni = 0; ni < 4; ++ni) {
          const int col = n0 + (w << 6) + (ni << 4) + (lane & 15);
          float zpre = aZ[mi * 4 + ni][q4] + bf2f(p.XP[(size_t)src * 1536 + 512 + col]) + p.wz_b[col];
          float hpre = aH[mi * 4 + ni][q4] + bf2f(p.XP[(size_t)src * 1536 + 1024 + col]) + p.wh_b[col];
          float zz = 1.f / (1.f + __expf(-zpre));
          float e2 = __expf(2.f * hpre);
          float th = 1.f - 2.f / (e2 + 1.f);
          float sumh = bf2f(p.A2h[(size_t)(m0 + row) * 512 + col]);
          float hn = (1.f - zz) * sumh + zz * th;
          p.hu[(size_t)e * 1024 + col] = f2bf(hn);
        }
      }
    }
    __syncthreads();
  }
}

// ---------------- phase C: u = h @ WUR, 4-wave 32r x 256c; reads/writes hu ----------------
struct CP {
  const int* sched;
  const unsigned short* WUR;
  const int* eIdx;
  unsigned short* hu;
  int B;
};

__global__ __launch_bounds__(256, 4) void gemmC_kernel(CP p, int r) {
  const int cnt = p.sched[1 + r];
  if (cnt == 0) return;
  const int M = cnt * p.B;
  const int nT = (M >> 5) << 1;
  const int qq = nT >> 3;
  __shared__ unsigned short lA[2][32 * 72];
  __shared__ int eL[32];
  const int tid = threadIdx.x, lane = tid & 63, w = tid >> 6;
  const int srow = tid >> 3, sc = (tid & 7) << 3;
  const int k8 = (lane >> 4) << 3;

  for (int t0 = blockIdx.x; t0 < nT; t0 += gridDim.x) {
    const int t = (t0 & 7) * qq + (t0 >> 3);
    const int mt = t >> 1, nb = t & 1;
    const int m0 = mt << 5, n0 = nb << 8;
    if (tid < 32) eL[tid] = p.eIdx[m0 + tid];
    __syncthreads();
    fx4 ac[8];
#pragma unroll
    for (int i = 0; i < 8; i++) { ac[i][0]=0.f; ac[i][1]=0.f; ac[i][2]=0.f; ac[i][3]=0.f; }
    const unsigned short* gbase = p.hu + (size_t)eL[srow] * 1024 + sc;
    s8v ra;
    {
      *(s8v*)&lA[0][srow * 72 + sc] = *(const s8v*)gbase;
      ra = *(const s8v*)(gbase + 64);
    }
    for (int ks = 0; ks < 8; ++ks) {
      const int cur = ks & 1;
      __syncthreads();
      if (ks < 7) {
        *(s8v*)&lA[cur ^ 1][srow * 72 + sc] = ra;
      }
      if (ks < 6) {
        ra = *(const s8v*)(gbase + ((ks + 2) << 6));
      }
#pragma unroll
      for (int sub = 0; sub < 2; ++sub) {
        const int kt = (ks << 1) + sub;
        s8v a[2];
#pragma unroll
        for (int mi = 0; mi < 2; ++mi)
          a[mi] = *(const s8v*)&lA[cur][((mi << 4) + (lane & 15)) * 72 + (sub << 5) + k8];
#pragma unroll
        for (int ni = 0; ni < 4; ++ni) {
          const int ntile = (n0 >> 4) + (w << 2) + ni;
          const size_t boff = ((((size_t)ntile << 4) + kt) * 64 + lane) << 3;
          const s8v bu = *(const s8v*)(p.WUR + boff);
#pragma unroll
          for (int mi = 0; mi < 2; ++mi) ac[mi * 4 + ni] = MFMA(a[mi], bu, ac[mi * 4 + ni]);
        }
      }
    }
#pragma unroll
    for (int mi = 0; mi < 2; ++mi) {
#pragma unroll
      for (int q4 = 0; q4 < 4; ++q4) {
        const int row = (mi << 4) + ((lane >> 4) << 2) + q4;
        const int e = eL[row];
#pragma unroll
        for (int ni = 0; ni < 4; ++ni) {
          const int col = n0 + (w << 6) + (ni << 4) + (lane & 15);
          p.hu[(size_t)e * 1024 + 512 + col] = f2bf(ac[mi * 4 + ni][q4]);
        }
      }
    }
    __syncthreads();
  }
}

// ---------------- hu(h half) -> f32 h convert (streaming, strided rows) ----------------
__global__ void cvt_kernel(const unsigned short* hu, float* h, int total8) {
  int idx = blockIdx.x * blockDim.x + threadIdx.x;
  int stride = gridDim.x * blockDim.x;
  for (int t = idx; t < total8; t += stride) {
    const int row = t >> 6;
    const int c8 = (t & 63) << 3;
    const s8v v = *(const s8v*)&hu[(size_t)row * 1024 + c8];
    float4 f0 = make_float4(bf2f((unsigned short)v[0]), bf2f((unsigned short)v[1]),
                            bf2f((unsigned short)v[2]), bf2f((unsigned short)v[3]));
    float4 f1 = make_float4(bf2f((unsigned short)v[4]), bf2f((unsigned short)v[5]),
                            bf2f((unsigned short)v[6]), bf2f((unsigned short)v[7]));
    *(float4*)&h[(size_t)row * 512 + c8] = f0;
    *(float4*)&h[(size_t)row * 512 + c8 + 4] = f1;
  }
}

// ---------------- root ----------------
__global__ void root_gather_kernel(const int* root_nodes, const int* root_in,
                                   const unsigned short* x_bf, const unsigned short* hu,
                                   unsigned short* Aroot, int B, int R0) {
  int lane = threadIdx.x & 63;
  int waveId = blockIdx.x * (blockDim.x >> 6) + (threadIdx.x >> 6);
  int totalWaves = gridDim.x * (blockDim.x >> 6);
  for (int b = waveId; b < B; b += totalWaves) {
    int c0 = lane << 3;
    int nd = root_nodes[b];
    *(s8v*)&Aroot[(size_t)b * 1024 + c0] = *(const s8v*)&x_bf[(size_t)nd * HD + c0];
    float s[8];
#pragma unroll
    for (int i = 0; i < 8; i++) s[i] = 0.f;
    for (int t = 0; t < R0; ++t) {
      int e = root_in[b * R0 + t];
      const s8v h8 = *(const s8v*)&hu[(size_t)e * 1024 + c0];
#pragma unroll
      for (int i = 0; i < 8; i++) s[i] += bf2f((unsigned short)h8[i]);
    }
    s8v sb;
#pragma unroll
    for (int i = 0; i < 8; i++) sb[i] = (short)f2bf(s[i]);
    *(s8v*)&Aroot[(size_t)b * 1024 + 512 + c0] = sb;
  }
}

// ---------------- root GEMM: 32r x 256c, 4 waves, K=1024, dbuf + reg-prefetch (R18) ----------------
__global__ __launch_bounds__(256, 4) void gemm_root_kernel(const unsigned short* Aroot,
                                                           const unsigned short* WO,
                                                           const float* wo_b, float* out, int B) {
  const int nT = (B >> 5) << 1;
  __shared__ unsigned short lA[2][32 * 72];
  const int tid = threadIdx.x, lane = tid & 63, w = tid >> 6;
  const int srow = tid >> 3, sc = (tid & 7) << 3;
  const int k8 = (lane >> 4) << 3;

  for (int t = blockIdx.x; t < nT; t += gridDim.x) {
    const int mt = t >> 1, nb = t & 1;
    const int m0 = mt << 5, n0 = nb << 8;
    fx4 ac[8];
#pragma unroll
    for (int i = 0; i < 8; i++) { ac[i][0]=0.f; ac[i][1]=0.f; ac[i][2]=0.f; ac[i][3]=0.f; }
    const unsigned short* gbase = Aroot + (size_t)(m0 + srow) * 1024 + sc;
    s8v ra;
    {
      *(s8v*)&lA[0][srow * 72 + sc] = *(const s8v*)gbase;
      ra = *(const s8v*)(gbase + 64);
    }
    for (int ks = 0; ks < 16; ++ks) {
      const int cur = ks & 1;
      __syncthreads();
      if (ks < 15) {
        *(s8v*)&lA[cur ^ 1][srow * 72 + sc] = ra;
      }
      if (ks < 14) {
        ra = *(const s8v*)(gbase + ((ks + 2) << 6));
      }
#pragma unroll
      for (int sub = 0; sub < 2; ++sub) {
        const int kt = (ks << 1) + sub;
        s8v a[2];
#pragma unroll
        for (int mi = 0; mi < 2; ++mi)
          a[mi] = *(const s8v*)&lA[cur][((mi << 4) + (lane & 15)) * 72 + (sub << 5) + k8];
#pragma unroll
        for (int ni = 0; ni < 4; ++ni) {
          const int ntile = (n0 >> 4) + (w << 2) + ni;
          const size_t boff = (((size_t)ntile * 32 + kt) * 64 + lane) << 3;
          const s8v b = *(const s8v*)(WO + boff);
#pragma unroll
          for (int mi = 0; mi < 2; ++mi) ac[mi * 4 + ni] = MFMA(a[mi], b, ac[mi * 4 + ni]);
        }
      }
    }
#pragma unroll
    for (int mi = 0; mi < 2; ++mi) {
#pragma unroll
      for (int q4 = 0; q4 < 4; ++q4) {
        const int row = (mi << 4) + ((lane >> 4) << 2) + q4;
        const int m = m0 + row;
#pragma unroll
        for (int ni = 0; ni < 4; ++ni) {
          const int col = n0 + (w << 6) + (ni << 4) + (lane & 15);
          float v = ac[mi * 4 + ni][q4] + wo_b[col];
          out[(size_t)m * HD + col] = v > 0.f ? v : 0.f;
        }
      }
    }
    __syncthreads();
  }
}

extern "C" void kernel_launch(void* const* d_in, const int* in_sizes, int n_in,
                              void* d_out, int out_size, void* d_ws, size_t ws_size,
                              hipStream_t stream) {
  const int* wid = (const int*)d_in[0];
  const int* edge_src = (const int*)d_in[1];
  const int* preds = (const int*)d_in[2];
  const int* root_in = (const int*)d_in[4];
  const int* root_nodes = (const int*)d_in[5];
  const float* emb = (const float*)d_in[6];
  const float* w_r = (const float*)d_in[7];
  const float* ur_w = (const float*)d_in[8];
  const float* ur_b = (const float*)d_in[9];
  const float* wz_w = (const float*)d_in[10];
  const float* wz_b = (const float*)d_in[11];
  const float* wh_w = (const float*)d_in[12];
  const float* wh_b = (const float*)d_in[13];
  const float* wo_w = (const float*)d_in[14];
  const float* wo_b = (const float*)d_in[15];

  const int BN = in_sizes[0];
  const int E = in_sizes[1];
  const int Bt = in_sizes[5];
  const int Epc = E / Bt;
  const int P = in_sizes[2] / (E + 1);
  const int R0 = in_sizes[4] / Bt;

  float* h = (float*)d_out;

  char* wp = (char*)d_ws;
  auto alloc = [&](size_t bytes) {
    char* r = wp;
    wp += (bytes + 255) & ~(size_t)255;
    return r;
  };
  unsigned short* x_bf = (unsigned short*)alloc((size_t)BN * 512 * 2);
  unsigned short* XP = (unsigned short*)alloc((size_t)BN * 1536 * 2);
  unsigned short* hu = (unsigned short*)alloc((size_t)E * 1024 * 2);
  unsigned short* A2h = (unsigned short*)alloc((size_t)E * 512 * 2);
  unsigned short* A2g = (unsigned short*)alloc((size_t)E * 512 * 2);
  int* eIdx = (int*)alloc((size_t)E * 4);
  int* srcIdx = (int*)alloc((size_t)E * 4);
  unsigned short* W1 = (unsigned short*)alloc((size_t)512 * 1536 * 2);
  unsigned short* WZB = (unsigned short*)alloc((size_t)512 * 512 * 2);
  unsigned short* WHB = (unsigned short*)alloc((size_t)512 * 512 * 2);
  unsigned short* WUR = (unsigned short*)alloc((size_t)512 * 512 * 2);
  unsigned short* WO = (unsigned short*)alloc((size_t)1024 * 512 * 2);
  unsigned short* Aroot = (unsigned short*)alloc((size_t)Bt * 1024 * 2);
  int* sched = (int*)alloc(8192);

  hipLaunchKernelGGL(pack_kernel, dim3(512), dim3(256), 0, stream,
                     w_r, ur_w, wz_w, wh_w, wo_w, W1, WZB, WHB, WUR, WO);
  hipLaunchKernelGGL(embed_kernel, dim3(1024), dim3(256), 0, stream, wid, emb, x_bf, BN);
  hipLaunchKernelGGL(schedule_kernel, dim3(1), dim3(64), 0, stream, preds, E, Epc, P, sched);
  hipLaunchKernelGGL(gemm_pre_kernel, dim3((BN / 128) * 6), dim3(512), 0, stream,
                     x_bf, W1, XP, BN);

  AP ap;
  ap.sched = sched; ap.preds = preds; ap.edge_src = edge_src;
  ap.ur_b = ur_b; ap.XP = XP; ap.hu_c = hu;
  ap.A2h = A2h; ap.A2g = A2g; ap.eIdx = eIdx; ap.srcIdx = srcIdx;
  ap.B = Bt; ap.Epc = Epc; ap.P = P; ap.E = E;

  BP bp;
  bp.sched = sched; bp.wz_b = wz_b; bp.wh_b = wh_b;
  bp.XP = XP; bp.A2h = A2h; bp.A2g = A2g;
  bp.WZB = WZB; bp.WHB = WHB;
  bp.eIdx = eIdx; bp.srcIdx = srcIdx;
  bp.hu = hu; bp.B = Bt;

  CP cp;
  cp.sched = sched; cp.WUR = WUR;
  cp.eIdx = eIdx; cp.hu = hu; cp.B = Bt;

  for (int r = 0; r < Epc && r < 31; ++r) {
    const int g = (r < 16) ? 1024 : 16;
    hipLaunchKernelGGL(gatherA_kernel, dim3(g), dim3(256), 0, stream, ap, r);
    hipLaunchKernelGGL(gemmB_kernel, dim3(g), dim3(256), 0, stream, bp, r);
    hipLaunchKernelGGL(gemmC_kernel, dim3(g), dim3(256), 0, stream, cp, r);
  }

  hipLaunchKernelGGL(cvt_kernel, dim3(2048), dim3(256), 0, stream, hu, h, E * 64);
  hipLaunchKernelGGL(root_gather_kernel, dim3(512), dim3(256), 0, stream,
                     root_nodes, root_in, x_bf, hu, Aroot, Bt, R0);
  hipLaunchKernelGGL(gemm_root_kernel, dim3((Bt / 32) * 2), dim3(256), 0, stream,
                     Aroot, WO, wo_b, h + (size_t)E * 512, Bt);
}

// Round 20
// 937.326 us; speedup vs baseline: 1.0137x; 1.0137x over previous
//
#include <hip/hip_runtime.h>
#include <hip/hip_bf16.h>
#include <cstddef>

#define HD 512

typedef short s8v __attribute__((ext_vector_type(8)));
typedef short s4v __attribute__((ext_vector_type(4)));
typedef float fx4 __attribute__((ext_vector_type(4)));

#define MFMA(a, b, c) __builtin_amdgcn_mfma_f32_16x16x32_bf16((a), (b), (c), 0, 0, 0)

__device__ __forceinline__ unsigned short f2bf(float f) {
  unsigned int u = __float_as_uint(f);
  unsigned int r = (u + 0x7fffu + ((u >> 16) & 1u)) >> 16;
  return (unsigned short)r;
}
__device__ __forceinline__ float bf2f(unsigned short u) {
  return __uint_as_float(((unsigned int)u) << 16);
}

// Swizzled B-operand layout for 16x16x32 MFMA (R1/R3-proven):
// element (k,n) -> chunk (ntile*KT + kt); lane = ((k&31)>>3)<<4 | (n&15); i = k&7
__device__ __forceinline__ size_t swz_off(int k, int n, int KT) {
  int kt = k >> 5, kr = k & 31;
  int nt = n >> 4, nr = n & 15;
  int lane = ((kr >> 3) << 4) | nr;
  int i = kr & 7;
  return ((((size_t)nt * KT + kt) * 64 + lane) << 3) + i;
}

// ---------------- pack weights (R4-proven layouts) ----------------
__global__ void pack_kernel(const float* w_r, const float* ur, const float* wz, const float* wh,
                            const float* wo,
                            unsigned short* W1, unsigned short* WZB, unsigned short* WHB,
                            unsigned short* WUR, unsigned short* WO) {
  int idx = blockIdx.x * blockDim.x + threadIdx.x;
  int stride = gridDim.x * blockDim.x;
  for (int t = idx; t < 512 * 1536; t += stride) {
    int k = t / 1536, n = t - k * 1536;
    float v;
    if (n < 512) v = w_r[k * 512 + n];
    else if (n < 1024) v = wz[k * 512 + (n - 512)];
    else v = wh[k * 512 + (n - 1024)];
    W1[swz_off(k, n, 16)] = f2bf(v);
  }
  for (int t = idx; t < 512 * 512; t += stride) {
    int k = t >> 9, n = t & 511;
    size_t o = swz_off(k, n, 16);
    WZB[o] = f2bf(wz[(512 + k) * 512 + n]);
    WHB[o] = f2bf(wh[(512 + k) * 512 + n]);
    WUR[o] = f2bf(ur[k * 512 + n]);
  }
  for (int t = idx; t < 1024 * 512; t += stride) {
    int k = t >> 9, n = t & 511;
    WO[swz_off(k, n, 32)] = f2bf(wo[k * 512 + n]);
  }
}

// ---------------- embedding gather ----------------
__global__ void embed_kernel(const int* wid, const float* emb, unsigned short* x_bf, int BN) {
  int idx = blockIdx.x * blockDim.x + threadIdx.x;
  int stride = gridDim.x * blockDim.x;
  int total = BN * (HD / 8);
  for (int t = idx; t < total; t += stride) {
    int nrow = t >> 6;
    int c8 = (t & 63) << 3;
    int w = wid[nrow];
    const float4* s = (const float4*)(emb + (size_t)w * HD + c8);
    float4 v0 = s[0], v1 = s[1];
    s8v o;
    o[0] = (short)f2bf(v0.x); o[1] = (short)f2bf(v0.y);
    o[2] = (short)f2bf(v0.z); o[3] = (short)f2bf(v0.w);
    o[4] = (short)f2bf(v1.x); o[5] = (short)f2bf(v1.y);
    o[6] = (short)f2bf(v1.z); o[7] = (short)f2bf(v1.w);
    *(s8v*)&x_bf[(size_t)nrow * HD + c8] = o;
  }
}

// ---------------- schedule: parallel LDS relaxation (R20) ----------------
// Old version re-read preds from global each of 31 iterations and had a
// single-threaded writeback (~2K serial global ops). New: preds cached in
// registers once; relaxation pure-LDS; output phase fully parallel.
__global__ void schedule_kernel(const int* preds, int E, int Epc, int P, int* sched) {
  __shared__ int rnd[64];
  int t = threadIdx.x;
  int pl[14];
  int np = 0;
  if (t < Epc) {
    for (int q = 0; q < P; ++q) {
      int pe = preds[t * P + q];
      if (pe < E && np < 14) pl[np++] = pe;  // tree-0 pred ids are < Epc
    }
  }
  rnd[t] = -1;
  __syncthreads();
  for (int it = 0; it <= Epc; ++it) {
    int newv = -1;
    if (t < Epc && rnd[t] < 0) {
      int mx = 0;
      bool ready = true;
      for (int q = 0; q < np; ++q) {
        int rp = rnd[pl[q]];
        if (rp < 0) { ready = false; break; }
        else if (rp + 1 > mx) mx = rp + 1;
      }
      if (ready) newv = mx;
    }
    __syncthreads();
    if (newv >= 0) rnd[t] = newv;
    __syncthreads();
  }
  // parallel output
  if (t < Epc) {
    const int myR = (rnd[t] > 30) ? 30 : rnd[t];
    int pos = 0;
    for (int e = 0; e < t; ++e) {
      int re = (rnd[e] > 30) ? 30 : rnd[e];
      if (re == myR) ++pos;
    }
    sched[33 + myR * 32 + pos] = t;
  }
  if (t < 31) {
    int c = 0;
    for (int e = 0; e < Epc; ++e) {
      int re = (rnd[e] > 30) ? 30 : rnd[e];
      if (re == t) ++c;
    }
    sched[1 + t] = c;
  }
  if (t == 0) {
    int R = 0;
    for (int e = 0; e < Epc; ++e) if (rnd[e] + 1 > R) R = rnd[e] + 1;
    if (R > 31) R = 31;
    sched[0] = R;
  }
}

// ---------------- XP = x_bf @ W1: 8-wave, 128r x 256c per block, 6 col-slabs (R8) ----------------
__global__ __launch_bounds__(512, 4) void gemm_pre_kernel(const unsigned short* x_bf,
                                                          const unsigned short* W1,
                                                          unsigned short* XP, int BN) {
  __shared__ unsigned short lA[2][128 * 72];
  const int nM = BN >> 7;
  const int slab = blockIdx.x / nM;
  const int mt = blockIdx.x - slab * nM;
  const int tid = threadIdx.x, lane = tid & 63, w = tid >> 6;
  const int wm = w & 1, wn = w >> 1;
  const int m0 = mt << 7;
  const int srow = tid >> 2, sc0 = (tid & 3) << 4;
  const int k8 = (lane >> 4) << 3;
  fx4 ac[16];
#pragma unroll
  for (int i = 0; i < 16; i++) { ac[i][0]=0.f; ac[i][1]=0.f; ac[i][2]=0.f; ac[i][3]=0.f; }
  const unsigned short* aptr = x_bf + (size_t)(m0 + srow) * 512 + sc0;
  s8v r0, r1;
  {
    r0 = *(const s8v*)aptr;
    r1 = *(const s8v*)(aptr + 8);
    *(s8v*)&lA[0][srow * 72 + sc0]     = r0;
    *(s8v*)&lA[0][srow * 72 + sc0 + 8] = r1;
    r0 = *(const s8v*)(aptr + 64);
    r1 = *(const s8v*)(aptr + 72);
  }
  for (int ks = 0; ks < 8; ++ks) {
    const int cur = ks & 1;
    __syncthreads();
    if (ks < 7) {
      *(s8v*)&lA[cur ^ 1][srow * 72 + sc0]     = r0;
      *(s8v*)&lA[cur ^ 1][srow * 72 + sc0 + 8] = r1;
    }
    if (ks < 6) {
      const unsigned short* g = aptr + ((ks + 2) << 6);
      r0 = *(const s8v*)g;
      r1 = *(const s8v*)(g + 8);
    }
#pragma unroll
    for (int sub = 0; sub < 2; ++sub) {
      const int kt = (ks << 1) + sub;
      s8v a[4];
#pragma unroll
      for (int mi = 0; mi < 4; ++mi)
        a[mi] = *(const s8v*)&lA[cur][((wm << 6) + (mi << 4) + (lane & 15)) * 72 + (sub << 5) + k8];
#pragma unroll
      for (int ni = 0; ni < 4; ++ni) {
        const int ntile = (slab << 4) + (wn << 2) + ni;
        const s8v b = *(const s8v*)(W1 + ((((size_t)ntile << 4) + kt) * 64 + lane) * 8);
#pragma unroll
        for (int mi = 0; mi < 4; ++mi) ac[mi * 4 + ni] = MFMA(a[mi], b, ac[mi * 4 + ni]);
      }
    }
  }
#pragma unroll
  for (int mi = 0; mi < 4; ++mi) {
#pragma unroll
    for (int q = 0; q < 4; ++q) {
      const int row = (wm << 6) + (mi << 4) + ((lane >> 4) << 2) + q;
#pragma unroll
      for (int ni = 0; ni < 4; ++ni) {
        const int col = (slab << 8) + (wn << 6) + (ni << 4) + (lane & 15);
        XP[(size_t)(m0 + row) * 1536 + col] = f2bf(ac[mi * 4 + ni][q]);
      }
    }
  }
}

// ---------------- phase A: gather; hu interleaved reads; contiguous per-wave chunks ----------------
struct AP {
  const int* sched;
  const int* preds;
  const int* edge_src;
  const float* ur_b;
  const unsigned short* XP;
  const unsigned short* hu_c;   // [E][1024]: h(0..511) | u(512..1023)
  unsigned short* A2h;
  unsigned short* A2g;
  int* eIdx;
  int* srcIdx;
  int B, Epc, P, E;
};

__global__ __launch_bounds__(256) void gatherA_kernel(AP p, int r) {
  const int cnt = p.sched[1 + r];
  if (cnt == 0) return;
  const int M = cnt * p.B;
  const int* lst = p.sched + 33 + r * 32;
  const int lane = threadIdx.x & 63;
  const int waveId = blockIdx.x * 4 + (threadIdx.x >> 6);
  const int totalWaves = gridDim.x * 4;
  const int chunk = (M + totalWaves - 1) / totalWaves;
  const int mBeg = waveId * chunk;
  const int mEnd = (mBeg + chunk < M) ? (mBeg + chunk) : M;
  for (int m = mBeg; m < mEnd; ++m) {
    const int b = m / cnt;
    const int j = m - b * cnt;
    const int e = b * p.Epc + lst[j];
    const int src = p.edge_src[e];
    if (lane == 0) { p.eIdx[m] = e; p.srcIdx[m] = src; }
    const int c0 = lane << 3;
    const s8v xr8 = *(const s8v*)&p.XP[(size_t)src * 1536 + c0];
    float xb[8], ub[8], sh[8], sg[8];
#pragma unroll
    for (int i = 0; i < 8; i++) {
      xb[i] = bf2f((unsigned short)xr8[i]);
      ub[i] = p.ur_b[c0 + i];
      sh[i] = 0.f; sg[i] = 0.f;
    }
    for (int t = 0; t < p.P; ++t) {
      const int pe = p.preds[(size_t)e * p.P + t];
      if (pe >= p.E) continue;
      const unsigned short* hurow = p.hu_c + (size_t)pe * 1024;
      const s8v h8 = *(const s8v*)&hurow[c0];
      const s8v u8 = *(const s8v*)&hurow[512 + c0];
#pragma unroll
      for (int i = 0; i < 8; i++) {
        const float hv = bf2f((unsigned short)h8[i]);
        const float rr = 1.f / (1.f + __expf(-(xb[i] + bf2f((unsigned short)u8[i]) + ub[i])));
        sh[i] += hv;
        sg[i] += rr * hv;
      }
    }
    s8v shb, sgb;
#pragma unroll
    for (int i = 0; i < 8; i++) { shb[i] = (short)f2bf(sh[i]); sgb[i] = (short)f2bf(sg[i]); }
    *(s8v*)&p.A2h[(size_t)m * 512 + c0] = shb;
    *(s8v*)&p.A2g[(size_t)m * 512 + c0] = sgb;
  }
}

// ---------------- phase B: 4-wave dual GEMM 32r x 256c (K=512) -> hu h-half ----------------
struct BP {
  const int* sched;
  const float* wz_b;
  const float* wh_b;
  const unsigned short* XP;
  const unsigned short* A2h;
  const unsigned short* A2g;
  const unsigned short* WZB;
  const unsigned short* WHB;
  const int* eIdx;
  const int* srcIdx;
  unsigned short* hu;
  int B;
};

__global__ __launch_bounds__(256, 4) void gemmB_kernel(BP p, int r) {
  const int cnt = p.sched[1 + r];
  if (cnt == 0) return;
  const int M = cnt * p.B;
  const int nT = (M >> 5) << 1;
  const int qq = nT >> 3;
  __shared__ unsigned short lZ[2][32 * 72];
  __shared__ unsigned short lH[2][32 * 72];
  __shared__ int eL[32];
  __shared__ int sL[32];
  const int tid = threadIdx.x, lane = tid & 63, w = tid >> 6;
  const int srow = tid >> 3, sc = (tid & 7) << 3;
  const int k8 = (lane >> 4) << 3;

  for (int t0 = blockIdx.x; t0 < nT; t0 += gridDim.x) {
    const int t = (t0 & 7) * qq + (t0 >> 3);
    const int mt = t >> 1, nb = t & 1;
    const int m0 = mt << 5, n0 = nb << 8;
    if (tid < 32) { eL[tid] = p.eIdx[m0 + tid]; sL[tid] = p.srcIdx[m0 + tid]; }
    fx4 aZ[8], aH[8];
#pragma unroll
    for (int i = 0; i < 8; i++) {
      aZ[i][0]=0.f; aZ[i][1]=0.f; aZ[i][2]=0.f; aZ[i][3]=0.f;
      aH[i][0]=0.f; aH[i][1]=0.f; aH[i][2]=0.f; aH[i][3]=0.f;
    }
    const size_t rbase = (size_t)(m0 + srow) * 512 + sc;
    s8v nh, ng;
    {
      *(s8v*)&lZ[0][srow * 72 + sc] = *(const s8v*)&p.A2h[rbase];
      *(s8v*)&lH[0][srow * 72 + sc] = *(const s8v*)&p.A2g[rbase];
      nh = *(const s8v*)&p.A2h[rbase + 64];
      ng = *(const s8v*)&p.A2g[rbase + 64];
    }
    for (int ks = 0; ks < 8; ++ks) {
      const int cur = ks & 1;
      __syncthreads();
      if (ks < 7) {
        *(s8v*)&lZ[cur ^ 1][srow * 72 + sc] = nh;
        *(s8v*)&lH[cur ^ 1][srow * 72 + sc] = ng;
      }
      if (ks < 6) {
        nh = *(const s8v*)&p.A2h[rbase + ((ks + 2) << 6)];
        ng = *(const s8v*)&p.A2g[rbase + ((ks + 2) << 6)];
      }
#pragma unroll
      for (int sub = 0; sub < 2; ++sub) {
        const int kt = (ks << 1) + sub;
        s8v az[2], ah[2];
#pragma unroll
        for (int mi = 0; mi < 2; ++mi) {
          const int ao = ((mi << 4) + (lane & 15)) * 72 + (sub << 5) + k8;
          az[mi] = *(const s8v*)&lZ[cur][ao];
          ah[mi] = *(const s8v*)&lH[cur][ao];
        }
#pragma unroll
        for (int ni = 0; ni < 4; ++ni) {
          const int ntile = (n0 >> 4) + (w << 2) + ni;
          const size_t boff = ((((size_t)ntile << 4) + kt) * 64 + lane) << 3;
          const s8v bz = *(const s8v*)(p.WZB + boff);
          const s8v bh = *(const s8v*)(p.WHB + boff);
#pragma unroll
          for (int mi = 0; mi < 2; ++mi) {
            aZ[mi * 4 + ni] = MFMA(az[mi], bz, aZ[mi * 4 + ni]);
            aH[mi * 4 + ni] = MFMA(ah[mi], bh, aH[mi * 4 + ni]);
          }
        }
      }
    }
#pragma unroll
    for (int mi = 0; mi < 2; ++mi) {
#pragma unroll
      for (int q4 = 0; q4 < 4; ++q4) {
        const int row = (mi << 4) + ((lane >> 4) << 2) + q4;
        const int e = eL[row];
        const int src = sL[row];
#pragma unroll
        for (int ni = 0; ni < 4; ++ni) {
          const int col = n0 + (w << 6) + (ni << 4) + (lane & 15);
          float zpre = aZ[mi * 4 + ni][q4] + bf2f(p.XP[(size_t)src * 1536 + 512 + col]) + p.wz_b[col];
          float hpre = aH[mi * 4 + ni][q4] + bf2f(p.XP[(size_t)src * 1536 + 1024 + col]) + p.wh_b[col];
          float zz = 1.f / (1.f + __expf(-zpre));
          float e2 = __expf(2.f * hpre);
          float th = 1.f - 2.f / (e2 + 1.f);
          float sumh = bf2f(p.A2h[(size_t)(m0 + row) * 512 + col]);
          float hn = (1.f - zz) * sumh + zz * th;
          p.hu[(size_t)e * 1024 + col] = f2bf(hn);
        }
      }
    }
    __syncthreads();
  }
}

// ---------------- phase C: u = h @ WUR, 4-wave 32r x 256c; reads/writes hu ----------------
struct CP {
  const int* sched;
  const unsigned short* WUR;
  const int* eIdx;
  unsigned short* hu;
  int B;
};

__global__ __launch_bounds__(256, 4) void gemmC_kernel(CP p, int r) {
  const int cnt = p.sched[1 + r];
  if (cnt == 0) return;
  const int M = cnt * p.B;
  const int nT = (M >> 5) << 1;
  const int qq = nT >> 3;
  __shared__ unsigned short lA[2][32 * 72];
  __shared__ int eL[32];
  const int tid = threadIdx.x, lane = tid & 63, w = tid >> 6;
  const int srow = tid >> 3, sc = (tid & 7) << 3;
  const int k8 = (lane >> 4) << 3;

  for (int t0 = blockIdx.x; t0 < nT; t0 += gridDim.x) {
    const int t = (t0 & 7) * qq + (t0 >> 3);
    const int mt = t >> 1, nb = t & 1;
    const int m0 = mt << 5, n0 = nb << 8;
    if (tid < 32) eL[tid] = p.eIdx[m0 + tid];
    __syncthreads();
    fx4 ac[8];
#pragma unroll
    for (int i = 0; i < 8; i++) { ac[i][0]=0.f; ac[i][1]=0.f; ac[i][2]=0.f; ac[i][3]=0.f; }
    const unsigned short* gbase = p.hu + (size_t)eL[srow] * 1024 + sc;
    s8v ra;
    {
      *(s8v*)&lA[0][srow * 72 + sc] = *(const s8v*)gbase;
      ra = *(const s8v*)(gbase + 64);
    }
    for (int ks = 0; ks < 8; ++ks) {
      const int cur = ks & 1;
      __syncthreads();
      if (ks < 7) {
        *(s8v*)&lA[cur ^ 1][srow * 72 + sc] = ra;
      }
      if (ks < 6) {
        ra = *(const s8v*)(gbase + ((ks + 2) << 6));
      }
#pragma unroll
      for (int sub = 0; sub < 2; ++sub) {
        const int kt = (ks << 1) + sub;
        s8v a[2];
#pragma unroll
        for (int mi = 0; mi < 2; ++mi)
          a[mi] = *(const s8v*)&lA[cur][((mi << 4) + (lane & 15)) * 72 + (sub << 5) + k8];
#pragma unroll
        for (int ni = 0; ni < 4; ++ni) {
          const int ntile = (n0 >> 4) + (w << 2) + ni;
          const size_t boff = ((((size_t)ntile << 4) + kt) * 64 + lane) << 3;
          const s8v bu = *(const s8v*)(p.WUR + boff);
#pragma unroll
          for (int mi = 0; mi < 2; ++mi) ac[mi * 4 + ni] = MFMA(a[mi], bu, ac[mi * 4 + ni]);
        }
      }
    }
#pragma unroll
    for (int mi = 0; mi < 2; ++mi) {
#pragma unroll
      for (int q4 = 0; q4 < 4; ++q4) {
        const int row = (mi << 4) + ((lane >> 4) << 2) + q4;
        const int e = eL[row];
#pragma unroll
        for (int ni = 0; ni < 4; ++ni) {
          const int col = n0 + (w << 6) + (ni << 4) + (lane & 15);
          p.hu[(size_t)e * 1024 + 512 + col] = f2bf(ac[mi * 4 + ni][q4]);
        }
      }
    }
    __syncthreads();
  }
}

// ---------------- hu(h half) -> f32 h convert (streaming, strided rows) ----------------
__global__ void cvt_kernel(const unsigned short* hu, float* h, int total8) {
  int idx = blockIdx.x * blockDim.x + threadIdx.x;
  int stride = gridDim.x * blockDim.x;
  for (int t = idx; t < total8; t += stride) {
    const int row = t >> 6;
    const int c8 = (t & 63) << 3;
    const s8v v = *(const s8v*)&hu[(size_t)row * 1024 + c8];
    float4 f0 = make_float4(bf2f((unsigned short)v[0]), bf2f((unsigned short)v[1]),
                            bf2f((unsigned short)v[2]), bf2f((unsigned short)v[3]));
    float4 f1 = make_float4(bf2f((unsigned short)v[4]), bf2f((unsigned short)v[5]),
                            bf2f((unsigned short)v[6]), bf2f((unsigned short)v[7]));
    *(float4*)&h[(size_t)row * 512 + c8] = f0;
    *(float4*)&h[(size_t)row * 512 + c8 + 4] = f1;
  }
}

// ---------------- root ----------------
__global__ void root_gather_kernel(const int* root_nodes, const int* root_in,
                                   const unsigned short* x_bf, const unsigned short* hu,
                                   unsigned short* Aroot, int B, int R0) {
  int lane = threadIdx.x & 63;
  int waveId = blockIdx.x * (blockDim.x >> 6) + (threadIdx.x >> 6);
  int totalWaves = gridDim.x * (blockDim.x >> 6);
  for (int b = waveId; b < B; b += totalWaves) {
    int c0 = lane << 3;
    int nd = root_nodes[b];
    *(s8v*)&Aroot[(size_t)b * 1024 + c0] = *(const s8v*)&x_bf[(size_t)nd * HD + c0];
    float s[8];
#pragma unroll
    for (int i = 0; i < 8; i++) s[i] = 0.f;
    for (int t = 0; t < R0; ++t) {
      int e = root_in[b * R0 + t];
      const s8v h8 = *(const s8v*)&hu[(size_t)e * 1024 + c0];
#pragma unroll
      for (int i = 0; i < 8; i++) s[i] += bf2f((unsigned short)h8[i]);
    }
    s8v sb;
#pragma unroll
    for (int i = 0; i < 8; i++) sb[i] = (short)f2bf(s[i]);
    *(s8v*)&Aroot[(size_t)b * 1024 + 512 + c0] = sb;
  }
}

// ---------------- root GEMM: 32r x 256c, 4 waves, K=1024, dbuf + reg-prefetch (R18) ----------------
__global__ __launch_bounds__(256, 4) void gemm_root_kernel(const unsigned short* Aroot,
                                                           const unsigned short* WO,
                                                           const float* wo_b, float* out, int B) {
  const int nT = (B >> 5) << 1;
  __shared__ unsigned short lA[2][32 * 72];
  const int tid = threadIdx.x, lane = tid & 63, w = tid >> 6;
  const int srow = tid >> 3, sc = (tid & 7) << 3;
  const int k8 = (lane >> 4) << 3;

  for (int t = blockIdx.x; t < nT; t += gridDim.x) {
    const int mt = t >> 1, nb = t & 1;
    const int m0 = mt << 5, n0 = nb << 8;
    fx4 ac[8];
#pragma unroll
    for (int i = 0; i < 8; i++) { ac[i][0]=0.f; ac[i][1]=0.f; ac[i][2]=0.f; ac[i][3]=0.f; }
    const unsigned short* gbase = Aroot + (size_t)(m0 + srow) * 1024 + sc;
    s8v ra;
    {
      *(s8v*)&lA[0][srow * 72 + sc] = *(const s8v*)gbase;
      ra = *(const s8v*)(gbase + 64);
    }
    for (int ks = 0; ks < 16; ++ks) {
      const int cur = ks & 1;
      __syncthreads();
      if (ks < 15) {
        *(s8v*)&lA[cur ^ 1][srow * 72 + sc] = ra;
      }
      if (ks < 14) {
        ra = *(const s8v*)(gbase + ((ks + 2) << 6));
      }
#pragma unroll
      for (int sub = 0; sub < 2; ++sub) {
        const int kt = (ks << 1) + sub;
        s8v a[2];
#pragma unroll
        for (int mi = 0; mi < 2; ++mi)
          a[mi] = *(const s8v*)&lA[cur][((mi << 4) + (lane & 15)) * 72 + (sub << 5) + k8];
#pragma unroll
        for (int ni = 0; ni < 4; ++ni) {
          const int ntile = (n0 >> 4) + (w << 2) + ni;
          const size_t boff = (((size_t)ntile * 32 + kt) * 64 + lane) << 3;
          const s8v b = *(const s8v*)(WO + boff);
#pragma unroll
          for (int mi = 0; mi < 2; ++mi) ac[mi * 4 + ni] = MFMA(a[mi], b, ac[mi * 4 + ni]);
        }
      }
    }
#pragma unroll
    for (int mi = 0; mi < 2; ++mi) {
#pragma unroll
      for (int q4 = 0; q4 < 4; ++q4) {
        const int row = (mi << 4) + ((lane >> 4) << 2) + q4;
        const int m = m0 + row;
#pragma unroll
        for (int ni = 0; ni < 4; ++ni) {
          const int col = n0 + (w << 6) + (ni << 4) + (lane & 15);
          float v = ac[mi * 4 + ni][q4] + wo_b[col];
          out[(size_t)m * HD + col] = v > 0.f ? v : 0.f;
        }
      }
    }
    __syncthreads();
  }
}

extern "C" void kernel_launch(void* const* d_in, const int* in_sizes, int n_in,
                              void* d_out, int out_size, void* d_ws, size_t ws_size,
                              hipStream_t stream) {
  const int* wid = (const int*)d_in[0];
  const int* edge_src = (const int*)d_in[1];
  const int* preds = (const int*)d_in[2];
  const int* root_in = (const int*)d_in[4];
  const int* root_nodes = (const int*)d_in[5];
  const float* emb = (const float*)d_in[6];
  const float* w_r = (const float*)d_in[7];
  const float* ur_w = (const float*)d_in[8];
  const float* ur_b = (const float*)d_in[9];
  const float* wz_w = (const float*)d_in[10];
  const float* wz_b = (const float*)d_in[11];
  const float* wh_w = (const float*)d_in[12];
  const float* wh_b = (const float*)d_in[13];
  const float* wo_w = (const float*)d_in[14];
  const float* wo_b = (const float*)d_in[15];

  const int BN = in_sizes[0];
  const int E = in_sizes[1];
  const int Bt = in_sizes[5];
  const int Epc = E / Bt;
  const int P = in_sizes[2] / (E + 1);
  const int R0 = in_sizes[4] / Bt;

  float* h = (float*)d_out;

  char* wp = (char*)d_ws;
  auto alloc = [&](size_t bytes) {
    char* r = wp;
    wp += (bytes + 255) & ~(size_t)255;
    return r;
  };
  unsigned short* x_bf = (unsigned short*)alloc((size_t)BN * 512 * 2);
  unsigned short* XP = (unsigned short*)alloc((size_t)BN * 1536 * 2);
  unsigned short* hu = (unsigned short*)alloc((size_t)E * 1024 * 2);
  unsigned short* A2h = (unsigned short*)alloc((size_t)E * 512 * 2);
  unsigned short* A2g = (unsigned short*)alloc((size_t)E * 512 * 2);
  int* eIdx = (int*)alloc((size_t)E * 4);
  int* srcIdx = (int*)alloc((size_t)E * 4);
  unsigned short* W1 = (unsigned short*)alloc((size_t)512 * 1536 * 2);
  unsigned short* WZB = (unsigned short*)alloc((size_t)512 * 512 * 2);
  unsigned short* WHB = (unsigned short*)alloc((size_t)512 * 512 * 2);
  unsigned short* WUR = (unsigned short*)alloc((size_t)512 * 512 * 2);
  unsigned short* WO = (unsigned short*)alloc((size_t)1024 * 512 * 2);
  unsigned short* Aroot = (unsigned short*)alloc((size_t)Bt * 1024 * 2);
  int* sched = (int*)alloc(8192);

  hipLaunchKernelGGL(pack_kernel, dim3(512), dim3(256), 0, stream,
                     w_r, ur_w, wz_w, wh_w, wo_w, W1, WZB, WHB, WUR, WO);
  hipLaunchKernelGGL(embed_kernel, dim3(1024), dim3(256), 0, stream, wid, emb, x_bf, BN);
  hipLaunchKernelGGL(schedule_kernel, dim3(1), dim3(64), 0, stream, preds, E, Epc, P, sched);
  hipLaunchKernelGGL(gemm_pre_kernel, dim3((BN / 128) * 6), dim3(512), 0, stream,
                     x_bf, W1, XP, BN);

  AP ap;
  ap.sched = sched; ap.preds = preds; ap.edge_src = edge_src;
  ap.ur_b = ur_b; ap.XP = XP; ap.hu_c = hu;
  ap.A2h = A2h; ap.A2g = A2g; ap.eIdx = eIdx; ap.srcIdx = srcIdx;
  ap.B = Bt; ap.Epc = Epc; ap.P = P; ap.E = E;

  BP bp;
  bp.sched = sched; bp.wz_b = wz_b; bp.wh_b = wh_b;
  bp.XP = XP; bp.A2h = A2h; bp.A2g = A2g;
  bp.WZB = WZB; bp.WHB = WHB;
  bp.eIdx = eIdx; bp.srcIdx = srcIdx;
  bp.hu = hu; bp.B = Bt;

  CP cp;
  cp.sched = sched; cp.WUR = WUR;
  cp.eIdx = eIdx; cp.hu = hu; cp.B = Bt;

  for (int r = 0; r < Epc && r < 31; ++r) {
    const int g = (r < 16) ? 1024 : 16;
    hipLaunchKernelGGL(gatherA_kernel, dim3(g), dim3(256), 0, stream, ap, r);
    hipLaunchKernelGGL(gemmB_kernel, dim3(g), dim3(256), 0, stream, bp, r);
    hipLaunchKernelGGL(gemmC_kernel, dim3(g), dim3(256), 0, stream, cp, r);
  }

  hipLaunchKernelGGL(cvt_kernel, dim3(2048), dim3(256), 0, stream, hu, h, E * 64);
  hipLaunchKernelGGL(root_gather_kernel, dim3(512), dim3(256), 0, stream,
                     root_nodes, root_in, x_bf, hu, Aroot, Bt, R0);
  hipLaunchKernelGGL(gemm_root_kernel, dim3((Bt / 32) * 2), dim3(256), 0, stream,
                     Aroot, WO, wo_b, h + (size_t)E * 512, Bt);
}

// Round 21
// 911.894 us; speedup vs baseline: 1.0419x; 1.0279x over previous
//
#include <hip/hip_runtime.h>
#include <hip/hip_bf16.h>
#include <cstddef>

#define HD 512

typedef short s8v __attribute__((ext_vector_type(8)));
typedef short s4v __attribute__((ext_vector_type(4)));
typedef float fx4 __attribute__((ext_vector_type(4)));

#define MFMA(a, b, c) __builtin_amdgcn_mfma_f32_16x16x32_bf16((a), (b), (c), 0, 0, 0)

__device__ __forceinline__ unsigned short f2bf(float f) {
  unsigned int u = __float_as_uint(f);
  unsigned int r = (u + 0x7fffu + ((u >> 16) & 1u)) >> 16;
  return (unsigned short)r;
}
__device__ __forceinline__ float bf2f(unsigned short u) {
  return __uint_as_float(((unsigned int)u) << 16);
}

// Swizzled B-operand layout for 16x16x32 MFMA (R1/R3-proven):
// element (k,n) -> chunk (ntile*KT + kt); lane = ((k&31)>>3)<<4 | (n&15); i = k&7
__device__ __forceinline__ size_t swz_off(int k, int n, int KT) {
  int kt = k >> 5, kr = k & 31;
  int nt = n >> 4, nr = n & 15;
  int lane = ((kr >> 3) << 4) | nr;
  int i = kr & 7;
  return ((((size_t)nt * KT + kt) * 64 + lane) << 3) + i;
}

// ---------------- pack weights (R4-proven layouts) ----------------
__global__ void pack_kernel(const float* w_r, const float* ur, const float* wz, const float* wh,
                            const float* wo,
                            unsigned short* W1, unsigned short* WZB, unsigned short* WHB,
                            unsigned short* WUR, unsigned short* WO) {
  int idx = blockIdx.x * blockDim.x + threadIdx.x;
  int stride = gridDim.x * blockDim.x;
  for (int t = idx; t < 512 * 1536; t += stride) {
    int k = t / 1536, n = t - k * 1536;
    float v;
    if (n < 512) v = w_r[k * 512 + n];
    else if (n < 1024) v = wz[k * 512 + (n - 512)];
    else v = wh[k * 512 + (n - 1024)];
    W1[swz_off(k, n, 16)] = f2bf(v);
  }
  for (int t = idx; t < 512 * 512; t += stride) {
    int k = t >> 9, n = t & 511;
    size_t o = swz_off(k, n, 16);
    WZB[o] = f2bf(wz[(512 + k) * 512 + n]);
    WHB[o] = f2bf(wh[(512 + k) * 512 + n]);
    WUR[o] = f2bf(ur[k * 512 + n]);
  }
  for (int t = idx; t < 1024 * 512; t += stride) {
    int k = t >> 9, n = t & 511;
    WO[swz_off(k, n, 32)] = f2bf(wo[k * 512 + n]);
  }
}

// ---------------- embedding gather ----------------
__global__ void embed_kernel(const int* wid, const float* emb, unsigned short* x_bf, int BN) {
  int idx = blockIdx.x * blockDim.x + threadIdx.x;
  int stride = gridDim.x * blockDim.x;
  int total = BN * (HD / 8);
  for (int t = idx; t < total; t += stride) {
    int nrow = t >> 6;
    int c8 = (t & 63) << 3;
    int w = wid[nrow];
    const float4* s = (const float4*)(emb + (size_t)w * HD + c8);
    float4 v0 = s[0], v1 = s[1];
    s8v o;
    o[0] = (short)f2bf(v0.x); o[1] = (short)f2bf(v0.y);
    o[2] = (short)f2bf(v0.z); o[3] = (short)f2bf(v0.w);
    o[4] = (short)f2bf(v1.x); o[5] = (short)f2bf(v1.y);
    o[6] = (short)f2bf(v1.z); o[7] = (short)f2bf(v1.w);
    *(s8v*)&x_bf[(size_t)nrow * HD + c8] = o;
  }
}

// ---------------- schedule: parallel LDS relaxation (R20) ----------------
__global__ void schedule_kernel(const int* preds, int E, int Epc, int P, int* sched) {
  __shared__ int rnd[64];
  int t = threadIdx.x;
  int pl[14];
  int np = 0;
  if (t < Epc) {
    for (int q = 0; q < P; ++q) {
      int pe = preds[t * P + q];
      if (pe < E && np < 14) pl[np++] = pe;
    }
  }
  rnd[t] = -1;
  __syncthreads();
  for (int it = 0; it <= Epc; ++it) {
    int newv = -1;
    if (t < Epc && rnd[t] < 0) {
      int mx = 0;
      bool ready = true;
      for (int q = 0; q < np; ++q) {
        int rp = rnd[pl[q]];
        if (rp < 0) { ready = false; break; }
        else if (rp + 1 > mx) mx = rp + 1;
      }
      if (ready) newv = mx;
    }
    __syncthreads();
    if (newv >= 0) rnd[t] = newv;
    __syncthreads();
  }
  if (t < Epc) {
    const int myR = (rnd[t] > 30) ? 30 : rnd[t];
    int pos = 0;
    for (int e = 0; e < t; ++e) {
      int re = (rnd[e] > 30) ? 30 : rnd[e];
      if (re == myR) ++pos;
    }
    sched[33 + myR * 32 + pos] = t;
  }
  if (t < 31) {
    int c = 0;
    for (int e = 0; e < Epc; ++e) {
      int re = (rnd[e] > 30) ? 30 : rnd[e];
      if (re == t) ++c;
    }
    sched[1 + t] = c;
  }
  if (t == 0) {
    int R = 0;
    for (int e = 0; e < Epc; ++e) if (rnd[e] + 1 > R) R = rnd[e] + 1;
    if (R > 31) R = 31;
    sched[0] = R;
  }
}

// ---------------- XP = x_bf @ W1: 8-wave, 128r x 256c per block, 6 col-slabs (R8) ----------------
__global__ __launch_bounds__(512, 4) void gemm_pre_kernel(const unsigned short* x_bf,
                                                          const unsigned short* W1,
                                                          unsigned short* XP, int BN) {
  __shared__ unsigned short lA[2][128 * 72];
  const int nM = BN >> 7;
  const int slab = blockIdx.x / nM;
  const int mt = blockIdx.x - slab * nM;
  const int tid = threadIdx.x, lane = tid & 63, w = tid >> 6;
  const int wm = w & 1, wn = w >> 1;
  const int m0 = mt << 7;
  const int srow = tid >> 2, sc0 = (tid & 3) << 4;
  const int k8 = (lane >> 4) << 3;
  fx4 ac[16];
#pragma unroll
  for (int i = 0; i < 16; i++) { ac[i][0]=0.f; ac[i][1]=0.f; ac[i][2]=0.f; ac[i][3]=0.f; }
  const unsigned short* aptr = x_bf + (size_t)(m0 + srow) * 512 + sc0;
  s8v r0, r1;
  {
    r0 = *(const s8v*)aptr;
    r1 = *(const s8v*)(aptr + 8);
    *(s8v*)&lA[0][srow * 72 + sc0]     = r0;
    *(s8v*)&lA[0][srow * 72 + sc0 + 8] = r1;
    r0 = *(const s8v*)(aptr + 64);
    r1 = *(const s8v*)(aptr + 72);
  }
  for (int ks = 0; ks < 8; ++ks) {
    const int cur = ks & 1;
    __syncthreads();
    if (ks < 7) {
      *(s8v*)&lA[cur ^ 1][srow * 72 + sc0]     = r0;
      *(s8v*)&lA[cur ^ 1][srow * 72 + sc0 + 8] = r1;
    }
    if (ks < 6) {
      const unsigned short* g = aptr + ((ks + 2) << 6);
      r0 = *(const s8v*)g;
      r1 = *(const s8v*)(g + 8);
    }
#pragma unroll
    for (int sub = 0; sub < 2; ++sub) {
      const int kt = (ks << 1) + sub;
      s8v a[4];
#pragma unroll
      for (int mi = 0; mi < 4; ++mi)
        a[mi] = *(const s8v*)&lA[cur][((wm << 6) + (mi << 4) + (lane & 15)) * 72 + (sub << 5) + k8];
#pragma unroll
      for (int ni = 0; ni < 4; ++ni) {
        const int ntile = (slab << 4) + (wn << 2) + ni;
        const s8v b = *(const s8v*)(W1 + ((((size_t)ntile << 4) + kt) * 64 + lane) * 8);
#pragma unroll
        for (int mi = 0; mi < 4; ++mi) ac[mi * 4 + ni] = MFMA(a[mi], b, ac[mi * 4 + ni]);
      }
    }
  }
#pragma unroll
  for (int mi = 0; mi < 4; ++mi) {
#pragma unroll
    for (int q = 0; q < 4; ++q) {
      const int row = (wm << 6) + (mi << 4) + ((lane >> 4) << 2) + q;
#pragma unroll
      for (int ni = 0; ni < 4; ++ni) {
        const int col = (slab << 8) + (wn << 6) + (ni << 4) + (lane & 15);
        XP[(size_t)(m0 + row) * 1536 + col] = f2bf(ac[mi * 4 + ni][q]);
      }
    }
  }
}

// ---------------- phase A: gather; hu interleaved reads; contiguous per-wave chunks ----------------
struct AP {
  const int* sched;
  const int* preds;
  const int* edge_src;
  const float* ur_b;
  const unsigned short* XP;
  const unsigned short* hu_c;   // [E][1024]: h(0..511) | u(512..1023)
  unsigned short* A2h;
  unsigned short* A2g;
  int* eIdx;
  int* srcIdx;
  int B, Epc, P, E;
};

__global__ __launch_bounds__(256) void gatherA_kernel(AP p, int r) {
  const int cnt = p.sched[1 + r];
  if (cnt == 0) return;
  const int M = cnt * p.B;
  const int* lst = p.sched + 33 + r * 32;
  const int lane = threadIdx.x & 63;
  const int waveId = blockIdx.x * 4 + (threadIdx.x >> 6);
  const int totalWaves = gridDim.x * 4;
  const int chunk = (M + totalWaves - 1) / totalWaves;
  const int mBeg = waveId * chunk;
  const int mEnd = (mBeg + chunk < M) ? (mBeg + chunk) : M;
  for (int m = mBeg; m < mEnd; ++m) {
    const int b = m / cnt;
    const int j = m - b * cnt;
    const int e = b * p.Epc + lst[j];
    const int src = p.edge_src[e];
    if (lane == 0) { p.eIdx[m] = e; p.srcIdx[m] = src; }
    const int c0 = lane << 3;
    const s8v xr8 = *(const s8v*)&p.XP[(size_t)src * 1536 + c0];
    float xb[8], ub[8], sh[8], sg[8];
#pragma unroll
    for (int i = 0; i < 8; i++) {
      xb[i] = bf2f((unsigned short)xr8[i]);
      ub[i] = p.ur_b[c0 + i];
      sh[i] = 0.f; sg[i] = 0.f;
    }
    for (int t = 0; t < p.P; ++t) {
      const int pe = p.preds[(size_t)e * p.P + t];
      if (pe >= p.E) continue;
      const unsigned short* hurow = p.hu_c + (size_t)pe * 1024;
      const s8v h8 = *(const s8v*)&hurow[c0];
      const s8v u8 = *(const s8v*)&hurow[512 + c0];
#pragma unroll
      for (int i = 0; i < 8; i++) {
        const float hv = bf2f((unsigned short)h8[i]);
        const float rr = 1.f / (1.f + __expf(-(xb[i] + bf2f((unsigned short)u8[i]) + ub[i])));
        sh[i] += hv;
        sg[i] += rr * hv;
      }
    }
    s8v shb, sgb;
#pragma unroll
    for (int i = 0; i < 8; i++) { shb[i] = (short)f2bf(sh[i]); sgb[i] = (short)f2bf(sg[i]); }
    *(s8v*)&p.A2h[(size_t)m * 512 + c0] = shb;
    *(s8v*)&p.A2g[(size_t)m * 512 + c0] = sgb;
  }
}

// ---------------- phase B: 4-wave dual GEMM 32r x 256c (K=512) -> hu h-half ----------------
// launch_bounds (256,2): big round is grid-limited to 4 blocks/CU anyway; the extra
// VGPR headroom lets the compiler pipeline the epilogue's 96 scattered loads.
struct BP {
  const int* sched;
  const float* wz_b;
  const float* wh_b;
  const unsigned short* XP;
  const unsigned short* A2h;
  const unsigned short* A2g;
  const unsigned short* WZB;
  const unsigned short* WHB;
  const int* eIdx;
  const int* srcIdx;
  unsigned short* hu;
  int B;
};

__global__ __launch_bounds__(256, 2) void gemmB_kernel(BP p, int r) {
  const int cnt = p.sched[1 + r];
  if (cnt == 0) return;
  const int M = cnt * p.B;
  const int nT = (M >> 5) << 1;
  const int qq = nT >> 3;
  __shared__ unsigned short lZ[2][32 * 72];
  __shared__ unsigned short lH[2][32 * 72];
  __shared__ int eL[32];
  __shared__ int sL[32];
  const int tid = threadIdx.x, lane = tid & 63, w = tid >> 6;
  const int srow = tid >> 3, sc = (tid & 7) << 3;
  const int k8 = (lane >> 4) << 3;

  for (int t0 = blockIdx.x; t0 < nT; t0 += gridDim.x) {
    const int t = (t0 & 7) * qq + (t0 >> 3);
    const int mt = t >> 1, nb = t & 1;
    const int m0 = mt << 5, n0 = nb << 8;
    if (tid < 32) { eL[tid] = p.eIdx[m0 + tid]; sL[tid] = p.srcIdx[m0 + tid]; }
    fx4 aZ[8], aH[8];
#pragma unroll
    for (int i = 0; i < 8; i++) {
      aZ[i][0]=0.f; aZ[i][1]=0.f; aZ[i][2]=0.f; aZ[i][3]=0.f;
      aH[i][0]=0.f; aH[i][1]=0.f; aH[i][2]=0.f; aH[i][3]=0.f;
    }
    const size_t rbase = (size_t)(m0 + srow) * 512 + sc;
    s8v nh, ng;
    {
      *(s8v*)&lZ[0][srow * 72 + sc] = *(const s8v*)&p.A2h[rbase];
      *(s8v*)&lH[0][srow * 72 + sc] = *(const s8v*)&p.A2g[rbase];
      nh = *(const s8v*)&p.A2h[rbase + 64];
      ng = *(const s8v*)&p.A2g[rbase + 64];
    }
    for (int ks = 0; ks < 8; ++ks) {
      const int cur = ks & 1;
      __syncthreads();
      if (ks < 7) {
        *(s8v*)&lZ[cur ^ 1][srow * 72 + sc] = nh;
        *(s8v*)&lH[cur ^ 1][srow * 72 + sc] = ng;
      }
      if (ks < 6) {
        nh = *(const s8v*)&p.A2h[rbase + ((ks + 2) << 6)];
        ng = *(const s8v*)&p.A2g[rbase + ((ks + 2) << 6)];
      }
#pragma unroll
      for (int sub = 0; sub < 2; ++sub) {
        const int kt = (ks << 1) + sub;
        s8v az[2], ah[2];
#pragma unroll
        for (int mi = 0; mi < 2; ++mi) {
          const int ao = ((mi << 4) + (lane & 15)) * 72 + (sub << 5) + k8;
          az[mi] = *(const s8v*)&lZ[cur][ao];
          ah[mi] = *(const s8v*)&lH[cur][ao];
        }
#pragma unroll
        for (int ni = 0; ni < 4; ++ni) {
          const int ntile = (n0 >> 4) + (w << 2) + ni;
          const size_t boff = ((((size_t)ntile << 4) + kt) * 64 + lane) << 3;
          const s8v bz = *(const s8v*)(p.WZB + boff);
          const s8v bh = *(const s8v*)(p.WHB + boff);
#pragma unroll
          for (int mi = 0; mi < 2; ++mi) {
            aZ[mi * 4 + ni] = MFMA(az[mi], bz, aZ[mi * 4 + ni]);
            aH[mi * 4 + ni] = MFMA(ah[mi], bh, aH[mi * 4 + ni]);
          }
        }
      }
    }
#pragma unroll
    for (int mi = 0; mi < 2; ++mi) {
#pragma unroll
      for (int q4 = 0; q4 < 4; ++q4) {
        const int row = (mi << 4) + ((lane >> 4) << 2) + q4;
        const int e = eL[row];
        const int src = sL[row];
#pragma unroll
        for (int ni = 0; ni < 4; ++ni) {
          const int col = n0 + (w << 6) + (ni << 4) + (lane & 15);
          float zpre = aZ[mi * 4 + ni][q4] + bf2f(p.XP[(size_t)src * 1536 + 512 + col]) + p.wz_b[col];
          float hpre = aH[mi * 4 + ni][q4] + bf2f(p.XP[(size_t)src * 1536 + 1024 + col]) + p.wh_b[col];
          float zz = 1.f / (1.f + __expf(-zpre));
          float e2 = __expf(2.f * hpre);
          float th = 1.f - 2.f / (e2 + 1.f);
          float sumh = bf2f(p.A2h[(size_t)(m0 + row) * 512 + col]);
          float hn = (1.f - zz) * sumh + zz * th;
          p.hu[(size_t)e * 1024 + col] = f2bf(hn);
        }
      }
    }
    __syncthreads();
  }
}

// ---------------- phase C: u = h @ WUR, 4-wave 32r x 256c; reads/writes hu ----------------
struct CP {
  const int* sched;
  const unsigned short* WUR;
  const int* eIdx;
  unsigned short* hu;
  int B;
};

__global__ __launch_bounds__(256, 2) void gemmC_kernel(CP p, int r) {
  const int cnt = p.sched[1 + r];
  if (cnt == 0) return;
  const int M = cnt * p.B;
  const int nT = (M >> 5) << 1;
  const int qq = nT >> 3;
  __shared__ unsigned short lA[2][32 * 72];
  __shared__ int eL[32];
  const int tid = threadIdx.x, lane = tid & 63, w = tid >> 6;
  const int srow = tid >> 3, sc = (tid & 7) << 3;
  const int k8 = (lane >> 4) << 3;

  for (int t0 = blockIdx.x; t0 < nT; t0 += gridDim.x) {
    const int t = (t0 & 7) * qq + (t0 >> 3);
    const int mt = t >> 1, nb = t & 1;
    const int m0 = mt << 5, n0 = nb << 8;
    if (tid < 32) eL[tid] = p.eIdx[m0 + tid];
    __syncthreads();
    fx4 ac[8];
#pragma unroll
    for (int i = 0; i < 8; i++) { ac[i][0]=0.f; ac[i][1]=0.f; ac[i][2]=0.f; ac[i][3]=0.f; }
    const unsigned short* gbase = p.hu + (size_t)eL[srow] * 1024 + sc;
    s8v ra;
    {
      *(s8v*)&lA[0][srow * 72 + sc] = *(const s8v*)gbase;
      ra = *(const s8v*)(gbase + 64);
    }
    for (int ks = 0; ks < 8; ++ks) {
      const int cur = ks & 1;
      __syncthreads();
      if (ks < 7) {
        *(s8v*)&lA[cur ^ 1][srow * 72 + sc] = ra;
      }
      if (ks < 6) {
        ra = *(const s8v*)(gbase + ((ks + 2) << 6));
      }
#pragma unroll
      for (int sub = 0; sub < 2; ++sub) {
        const int kt = (ks << 1) + sub;
        s8v a[2];
#pragma unroll
        for (int mi = 0; mi < 2; ++mi)
          a[mi] = *(const s8v*)&lA[cur][((mi << 4) + (lane & 15)) * 72 + (sub << 5) + k8];
#pragma unroll
        for (int ni = 0; ni < 4; ++ni) {
          const int ntile = (n0 >> 4) + (w << 2) + ni;
          const size_t boff = ((((size_t)ntile << 4) + kt) * 64 + lane) << 3;
          const s8v bu = *(const s8v*)(p.WUR + boff);
#pragma unroll
          for (int mi = 0; mi < 2; ++mi) ac[mi * 4 + ni] = MFMA(a[mi], bu, ac[mi * 4 + ni]);
        }
      }
    }
#pragma unroll
    for (int mi = 0; mi < 2; ++mi) {
#pragma unroll
      for (int q4 = 0; q4 < 4; ++q4) {
        const int row = (mi << 4) + ((lane >> 4) << 2) + q4;
        const int e = eL[row];
#pragma unroll
        for (int ni = 0; ni < 4; ++ni) {
          const int col = n0 + (w << 6) + (ni << 4) + (lane & 15);
          p.hu[(size_t)e * 1024 + 512 + col] = f2bf(ac[mi * 4 + ni][q4]);
        }
      }
    }
    __syncthreads();
  }
}

// ---------------- hu(h half) -> f32 h convert (streaming, strided rows) ----------------
__global__ void cvt_kernel(const unsigned short* hu, float* h, int total8) {
  int idx = blockIdx.x * blockDim.x + threadIdx.x;
  int stride = gridDim.x * blockDim.x;
  for (int t = idx; t < total8; t += stride) {
    const int row = t >> 6;
    const int c8 = (t & 63) << 3;
    const s8v v = *(const s8v*)&hu[(size_t)row * 1024 + c8];
    float4 f0 = make_float4(bf2f((unsigned short)v[0]), bf2f((unsigned short)v[1]),
                            bf2f((unsigned short)v[2]), bf2f((unsigned short)v[3]));
    float4 f1 = make_float4(bf2f((unsigned short)v[4]), bf2f((unsigned short)v[5]),
                            bf2f((unsigned short)v[6]), bf2f((unsigned short)v[7]));
    *(float4*)&h[(size_t)row * 512 + c8] = f0;
    *(float4*)&h[(size_t)row * 512 + c8 + 4] = f1;
  }
}

// ---------------- root ----------------
__global__ void root_gather_kernel(const int* root_nodes, const int* root_in,
                                   const unsigned short* x_bf, const unsigned short* hu,
                                   unsigned short* Aroot, int B, int R0) {
  int lane = threadIdx.x & 63;
  int waveId = blockIdx.x * (blockDim.x >> 6) + (threadIdx.x >> 6);
  int totalWaves = gridDim.x * (blockDim.x >> 6);
  for (int b = waveId; b < B; b += totalWaves) {
    int c0 = lane << 3;
    int nd = root_nodes[b];
    *(s8v*)&Aroot[(size_t)b * 1024 + c0] = *(const s8v*)&x_bf[(size_t)nd * HD + c0];
    float s[8];
#pragma unroll
    for (int i = 0; i < 8; i++) s[i] = 0.f;
    for (int t = 0; t < R0; ++t) {
      int e = root_in[b * R0 + t];
      const s8v h8 = *(const s8v*)&hu[(size_t)e * 1024 + c0];
#pragma unroll
      for (int i = 0; i < 8; i++) s[i] += bf2f((unsigned short)h8[i]);
    }
    s8v sb;
#pragma unroll
    for (int i = 0; i < 8; i++) sb[i] = (short)f2bf(s[i]);
    *(s8v*)&Aroot[(size_t)b * 1024 + 512 + c0] = sb;
  }
}

// ---------------- root GEMM: 32r x 256c, 4 waves, K=1024, dbuf + reg-prefetch (R18) ----------------
__global__ __launch_bounds__(256, 2) void gemm_root_kernel(const unsigned short* Aroot,
                                                           const unsigned short* WO,
                                                           const float* wo_b, float* out, int B) {
  const int nT = (B >> 5) << 1;
  __shared__ unsigned short lA[2][32 * 72];
  const int tid = threadIdx.x, lane = tid & 63, w = tid >> 6;
  const int srow = tid >> 3, sc = (tid & 7) << 3;
  const int k8 = (lane >> 4) << 3;

  for (int t = blockIdx.x; t < nT; t += gridDim.x) {
    const int mt = t >> 1, nb = t & 1;
    const int m0 = mt << 5, n0 = nb << 8;
    fx4 ac[8];
#pragma unroll
    for (int i = 0; i < 8; i++) { ac[i][0]=0.f; ac[i][1]=0.f; ac[i][2]=0.f; ac[i][3]=0.f; }
    const unsigned short* gbase = Aroot + (size_t)(m0 + srow) * 1024 + sc;
    s8v ra;
    {
      *(s8v*)&lA[0][srow * 72 + sc] = *(const s8v*)gbase;
      ra = *(const s8v*)(gbase + 64);
    }
    for (int ks = 0; ks < 16; ++ks) {
      const int cur = ks & 1;
      __syncthreads();
      if (ks < 15) {
        *(s8v*)&lA[cur ^ 1][srow * 72 + sc] = ra;
      }
      if (ks < 14) {
        ra = *(const s8v*)(gbase + ((ks + 2) << 6));
      }
#pragma unroll
      for (int sub = 0; sub < 2; ++sub) {
        const int kt = (ks << 1) + sub;
        s8v a[2];
#pragma unroll
        for (int mi = 0; mi < 2; ++mi)
          a[mi] = *(const s8v*)&lA[cur][((mi << 4) + (lane & 15)) * 72 + (sub << 5) + k8];
#pragma unroll
        for (int ni = 0; ni < 4; ++ni) {
          const int ntile = (n0 >> 4) + (w << 2) + ni;
          const size_t boff = (((size_t)ntile * 32 + kt) * 64 + lane) << 3;
          const s8v b = *(const s8v*)(WO + boff);
#pragma unroll
          for (int mi = 0; mi < 2; ++mi) ac[mi * 4 + ni] = MFMA(a[mi], b, ac[mi * 4 + ni]);
        }
      }
    }
#pragma unroll
    for (int mi = 0; mi < 2; ++mi) {
#pragma unroll
      for (int q4 = 0; q4 < 4; ++q4) {
        const int row = (mi << 4) + ((lane >> 4) << 2) + q4;
        const int m = m0 + row;
#pragma unroll
        for (int ni = 0; ni < 4; ++ni) {
          const int col = n0 + (w << 6) + (ni << 4) + (lane & 15);
          float v = ac[mi * 4 + ni][q4] + wo_b[col];
          out[(size_t)m * HD + col] = v > 0.f ? v : 0.f;
        }
      }
    }
    __syncthreads();
  }
}

extern "C" void kernel_launch(void* const* d_in, const int* in_sizes, int n_in,
                              void* d_out, int out_size, void* d_ws, size_t ws_size,
                              hipStream_t stream) {
  const int* wid = (const int*)d_in[0];
  const int* edge_src = (const int*)d_in[1];
  const int* preds = (const int*)d_in[2];
  const int* root_in = (const int*)d_in[4];
  const int* root_nodes = (const int*)d_in[5];
  const float* emb = (const float*)d_in[6];
  const float* w_r = (const float*)d_in[7];
  const float* ur_w = (const float*)d_in[8];
  const float* ur_b = (const float*)d_in[9];
  const float* wz_w = (const float*)d_in[10];
  const float* wz_b = (const float*)d_in[11];
  const float* wh_w = (const float*)d_in[12];
  const float* wh_b = (const float*)d_in[13];
  const float* wo_w = (const float*)d_in[14];
  const float* wo_b = (const float*)d_in[15];

  const int BN = in_sizes[0];
  const int E = in_sizes[1];
  const int Bt = in_sizes[5];
  const int Epc = E / Bt;
  const int P = in_sizes[2] / (E + 1);
  const int R0 = in_sizes[4] / Bt;

  float* h = (float*)d_out;

  char* wp = (char*)d_ws;
  auto alloc = [&](size_t bytes) {
    char* r = wp;
    wp += (bytes + 255) & ~(size_t)255;
    return r;
  };
  unsigned short* x_bf = (unsigned short*)alloc((size_t)BN * 512 * 2);
  unsigned short* XP = (unsigned short*)alloc((size_t)BN * 1536 * 2);
  unsigned short* hu = (unsigned short*)alloc((size_t)E * 1024 * 2);
  unsigned short* A2h = (unsigned short*)alloc((size_t)E * 512 * 2);
  unsigned short* A2g = (unsigned short*)alloc((size_t)E * 512 * 2);
  int* eIdx = (int*)alloc((size_t)E * 4);
  int* srcIdx = (int*)alloc((size_t)E * 4);
  unsigned short* W1 = (unsigned short*)alloc((size_t)512 * 1536 * 2);
  unsigned short* WZB = (unsigned short*)alloc((size_t)512 * 512 * 2);
  unsigned short* WHB = (unsigned short*)alloc((size_t)512 * 512 * 2);
  unsigned short* WUR = (unsigned short*)alloc((size_t)512 * 512 * 2);
  unsigned short* WO = (unsigned short*)alloc((size_t)1024 * 512 * 2);
  unsigned short* Aroot = (unsigned short*)alloc((size_t)Bt * 1024 * 2);
  int* sched = (int*)alloc(8192);

  hipLaunchKernelGGL(pack_kernel, dim3(512), dim3(256), 0, stream,
                     w_r, ur_w, wz_w, wh_w, wo_w, W1, WZB, WHB, WUR, WO);
  hipLaunchKernelGGL(embed_kernel, dim3(1024), dim3(256), 0, stream, wid, emb, x_bf, BN);
  hipLaunchKernelGGL(schedule_kernel, dim3(1), dim3(64), 0, stream, preds, E, Epc, P, sched);
  hipLaunchKernelGGL(gemm_pre_kernel, dim3((BN / 128) * 6), dim3(512), 0, stream,
                     x_bf, W1, XP, BN);

  AP ap;
  ap.sched = sched; ap.preds = preds; ap.edge_src = edge_src;
  ap.ur_b = ur_b; ap.XP = XP; ap.hu_c = hu;
  ap.A2h = A2h; ap.A2g = A2g; ap.eIdx = eIdx; ap.srcIdx = srcIdx;
  ap.B = Bt; ap.Epc = Epc; ap.P = P; ap.E = E;

  BP bp;
  bp.sched = sched; bp.wz_b = wz_b; bp.wh_b = wh_b;
  bp.XP = XP; bp.A2h = A2h; bp.A2g = A2g;
  bp.WZB = WZB; bp.WHB = WHB;
  bp.eIdx = eIdx; bp.srcIdx = srcIdx;
  bp.hu = hu; bp.B = Bt;

  CP cp;
  cp.sched = sched; cp.WUR = WUR;
  cp.eIdx = eIdx; cp.hu = hu; cp.B = Bt;

  for (int r = 0; r < Epc && r < 31; ++r) {
    const int g = (r < 16) ? 1024 : 16;
    hipLaunchKernelGGL(gatherA_kernel, dim3(g), dim3(256), 0, stream, ap, r);
    hipLaunchKernelGGL(gemmB_kernel, dim3(g), dim3(256), 0, stream, bp, r);
    hipLaunchKernelGGL(gemmC_kernel, dim3(g), dim3(256), 0, stream, cp, r);
  }

  hipLaunchKernelGGL(cvt_kernel, dim3(2048), dim3(256), 0, stream, hu, h, E * 64);
  hipLaunchKernelGGL(root_gather_kernel, dim3(512), dim3(256), 0, stream,
                     root_nodes, root_in, x_bf, hu, Aroot, Bt, R0);
  hipLaunchKernelGGL(gemm_root_kernel, dim3((Bt / 32) * 2), dim3(256), 0, stream,
                     Aroot, WO, wo_b, h + (size_t)E * 512, Bt);
}